// Round 1
// baseline (323.827 us; speedup 1.0000x reference)
//
#include <hip/hip_runtime.h>
#include <math.h>

#define H 2048

__device__ __forceinline__ float sigmoidf_(float v) {
    return 1.0f / (1.0f + expf(-v));
}

__device__ __forceinline__ float wave_reduce_sum(float v) {
    // 64-lane wave on CDNA
    v += __shfl_down(v, 32, 64);
    v += __shfl_down(v, 16, 64);
    v += __shfl_down(v, 8, 64);
    v += __shfl_down(v, 4, 64);
    v += __shfl_down(v, 2, 64);
    v += __shfl_down(v, 1, 64);
    return v;
}

// Layer 0: input is a scalar x, so the Wih0 contribution is x * Wih0[row].
// One block per output element t. 4 waves, wave w computes dot(Whh[w*H+t,:], hin).
__global__ __launch_bounds__(256)
void lstm_layer0(const float* __restrict__ Wih0,  // [4H] (4H x 1)
                 const float* __restrict__ Whh,   // [4H, H]
                 const float* __restrict__ bih,
                 const float* __restrict__ bhh,
                 const float* __restrict__ xs,    // [1]
                 const float* __restrict__ hin,   // [H]
                 const float* __restrict__ cin,   // [H]
                 float* __restrict__ hout,        // [H]
                 float* __restrict__ cout)        // [H]
{
    __shared__ float hv[H];
    __shared__ float dots[4];
    const int t = blockIdx.x;
    const int tid = threadIdx.x;

    // stage hin into LDS (2048 floats = 512 float4; 256 threads x 2)
    {
        const float4* h4 = (const float4*)hin;
        float4* hs = (float4*)hv;
        hs[tid] = h4[tid];
        hs[tid + 256] = h4[tid + 256];
    }
    __syncthreads();

    const int w = tid >> 6;      // wave 0..3 -> gate i,f,g,o
    const int lane = tid & 63;
    const size_t row = (size_t)w * H + t;
    const float4* Wr = (const float4*)(Whh + row * H);
    const float4* v4 = (const float4*)hv;

    float acc = 0.0f;
#pragma unroll
    for (int k = 0; k < 8; ++k) {
        float4 a = Wr[lane + 64 * k];
        float4 b = v4[lane + 64 * k];
        acc += a.x * b.x + a.y * b.y + a.z * b.z + a.w * b.w;
    }
    acc = wave_reduce_sum(acc);
    if (lane == 0) dots[w] = acc;
    __syncthreads();

    if (tid == 0) {
        const float x = xs[0];
        float gi = dots[0] + x * Wih0[t]         + bih[t]         + bhh[t];
        float gf = dots[1] + x * Wih0[H + t]     + bih[H + t]     + bhh[H + t];
        float gg = dots[2] + x * Wih0[2 * H + t] + bih[2 * H + t] + bhh[2 * H + t];
        float go = dots[3] + x * Wih0[3 * H + t] + bih[3 * H + t] + bhh[3 * H + t];
        float c2 = sigmoidf_(gf) * cin[t] + sigmoidf_(gi) * tanhf(gg);
        float h2 = sigmoidf_(go) * tanhf(c2);
        cout[t] = c2;
        hout[t] = h2;
    }
}

// Layers 1,2: both Wih and Whh are [4H, H].
// One block per output element t. 8 waves: waves 0-3 -> Wih rows, 4-7 -> Whh rows.
__global__ __launch_bounds__(512)
void lstm_layer_mat(const float* __restrict__ Wih,  // [4H, H]
                    const float* __restrict__ Whh,  // [4H, H]
                    const float* __restrict__ bih,
                    const float* __restrict__ bhh,
                    const float* __restrict__ xin,  // [H] (prev layer h)
                    const float* __restrict__ hin,  // [H]
                    const float* __restrict__ cin,  // [H]
                    float* __restrict__ hout,       // [H]
                    float* __restrict__ cout)       // [H]
{
    __shared__ float xv[H];
    __shared__ float hv[H];
    __shared__ float dots[8];
    const int t = blockIdx.x;
    const int tid = threadIdx.x;

    // stage both vectors into LDS (each 512 float4; 512 threads x 1)
    {
        const float4* x4 = (const float4*)xin;
        const float4* h4 = (const float4*)hin;
        ((float4*)xv)[tid] = x4[tid];
        ((float4*)hv)[tid] = h4[tid];
    }
    __syncthreads();

    const int w = tid >> 6;       // 0..7
    const int lane = tid & 63;
    const int gate = w & 3;       // 0..3
    const float* W = (w < 4) ? Wih : Whh;
    const float* v = (w < 4) ? xv : hv;
    const size_t row = (size_t)gate * H + t;
    const float4* Wr = (const float4*)(W + row * H);
    const float4* v4 = (const float4*)v;

    float acc = 0.0f;
#pragma unroll
    for (int k = 0; k < 8; ++k) {
        float4 a = Wr[lane + 64 * k];
        float4 b = v4[lane + 64 * k];
        acc += a.x * b.x + a.y * b.y + a.z * b.z + a.w * b.w;
    }
    acc = wave_reduce_sum(acc);
    if (lane == 0) dots[w] = acc;
    __syncthreads();

    if (tid == 0) {
        float gi = dots[0] + dots[4] + bih[t]         + bhh[t];
        float gf = dots[1] + dots[5] + bih[H + t]     + bhh[H + t];
        float gg = dots[2] + dots[6] + bih[2 * H + t] + bhh[2 * H + t];
        float go = dots[3] + dots[7] + bih[3 * H + t] + bhh[3 * H + t];
        float c2 = sigmoidf_(gf) * cin[t] + sigmoidf_(gi) * tanhf(gg);
        float h2 = sigmoidf_(go) * tanhf(c2);
        cout[t] = c2;
        hout[t] = h2;
    }
}

// y = dot(Wout, h) + bout   (single block)
__global__ __launch_bounds__(256)
void out_proj(const float* __restrict__ Wout,  // [H]
              const float* __restrict__ bout,  // [1]
              const float* __restrict__ h,     // [H]
              float* __restrict__ y)
{
    __shared__ float part[4];
    const int tid = threadIdx.x;
    const float4* W4 = (const float4*)Wout;
    const float4* h4 = (const float4*)h;
    float acc = 0.0f;
#pragma unroll
    for (int k = 0; k < 2; ++k) {
        int i = tid + 256 * k;
        float4 a = W4[i];
        float4 b = h4[i];
        acc += a.x * b.x + a.y * b.y + a.z * b.z + a.w * b.w;
    }
    acc = wave_reduce_sum(acc);
    if ((tid & 63) == 0) part[tid >> 6] = acc;
    __syncthreads();
    if (tid == 0) y[0] = part[0] + part[1] + part[2] + part[3] + bout[0];
}

extern "C" void kernel_launch(void* const* d_in, const int* in_sizes, int n_in,
                              void* d_out, int out_size, void* d_ws, size_t ws_size,
                              hipStream_t stream) {
    const float* x    = (const float*)d_in[0];
    const float* hin  = (const float*)d_in[1];   // [3,1,H]
    const float* cin  = (const float*)d_in[2];   // [3,1,H]
    const float* Wih0 = (const float*)d_in[3];
    const float* Whh0 = (const float*)d_in[4];
    const float* bih0 = (const float*)d_in[5];
    const float* bhh0 = (const float*)d_in[6];
    const float* Wih1 = (const float*)d_in[7];
    const float* Whh1 = (const float*)d_in[8];
    const float* bih1 = (const float*)d_in[9];
    const float* bhh1 = (const float*)d_in[10];
    const float* Wih2 = (const float*)d_in[11];
    const float* Whh2 = (const float*)d_in[12];
    const float* bih2 = (const float*)d_in[13];
    const float* bhh2 = (const float*)d_in[14];
    const float* Wout = (const float*)d_in[15];
    const float* bout = (const float*)d_in[16];

    float* out = (float*)d_out;
    float* y  = out;            // [1]
    float* hN = out + 1;        // [3,H]
    float* cN = out + 1 + 3 * H; // [3,H]

    lstm_layer0<<<H, 256, 0, stream>>>(Wih0, Whh0, bih0, bhh0, x,
                                       hin, cin, hN, cN);
    lstm_layer_mat<<<H, 512, 0, stream>>>(Wih1, Whh1, bih1, bhh1,
                                          hN, hin + H, cin + H,
                                          hN + H, cN + H);
    lstm_layer_mat<<<H, 512, 0, stream>>>(Wih2, Whh2, bih2, bhh2,
                                          hN + H, hin + 2 * H, cin + 2 * H,
                                          hN + 2 * H, cN + 2 * H);
    out_proj<<<1, 256, 0, stream>>>(Wout, bout, hN + 2 * H, y);
}